// Round 10
// baseline (380.220 us; speedup 1.0000x reference)
//
#include <hip/hip_runtime.h>
#include <hip/hip_cooperative_groups.h>
#include <math.h>

#define D_MODEL 768
#define HS 64
#define BATCH 8
#define SEQ 2048
#define SCALE 0.125f
#define KSPLIT 8
#define KCHUNK (SEQ / KSPLIT)   // 256

namespace cg = cooperative_groups;

typedef _Float16 half_t;
typedef __attribute__((ext_vector_type(8))) _Float16 half8;
typedef __attribute__((ext_vector_type(4))) float floatx4;

// ---------------------------------------------------------------
// Kernel 1: W fp32 [D][H] x3 -> Wt fp16 [3*H][D]
// ---------------------------------------------------------------
__global__ __launch_bounds__(256)
void wconv_kernel(const float* __restrict__ Wq, const float* __restrict__ Wk,
                  const float* __restrict__ Wv, half_t* __restrict__ Wt)
{
    int m = blockIdx.x >> 6;
    int h = blockIdx.x & 63;
    const float* W = (m == 0) ? Wq : ((m == 1) ? Wk : Wv);
    half_t* dst = Wt + (size_t)blockIdx.x * D_MODEL;
    for (int k = threadIdx.x; k < D_MODEL; k += 256)
        dst[k] = (half_t)W[(size_t)k * HS + h];
}

// ===============================================================
// Cooperative monolith. LDS union <= 28 KB so even a conservative
// 64KB-per-CU occupancy model admits 2 blocks/CU -> 512 co-resident.
// proj: single-buffered tiles, 2 barriers/iter, reg prefetch after
// barrier 1. attn: single-buffered K/V + 16-row ps, 2 barriers/iter.
// ===============================================================
union SmemU {
    struct {                        // 28,672 B
        half_t xs[32 * 64];
        half_t wt[192 * 64];
    } proj;
    struct {                        // 25,600 B
        half_t ks[64 * 64];
        half_t vs[64 * 64];
        half_t ps[4][16][72];
    } attn;
};

__global__ __launch_bounds__(256, 2)
void fused_kernel(const float* __restrict__ x, const half_t* __restrict__ Wt,
                  const float* __restrict__ bq, const float* __restrict__ bk,
                  const float* __restrict__ bv,
                  float* __restrict__ out,
                  half_t* __restrict__ Qh, half_t* __restrict__ Kh,
                  half_t* __restrict__ Vt,
                  half_t* __restrict__ Opart, float* __restrict__ lpart)
{
    __shared__ SmemU sm;
    cg::grid_group grid = cg::this_grid();

    const int bid = blockIdx.x;
    const int tid = threadIdx.x;
    const int w = tid >> 6;
    const int lane = tid & 63;
    const int l15 = lane & 15;
    const int quad = lane >> 4;

    // ================= Phase 1: QKV projection =================
    {
        const long row0 = (long)bid * 32;

        floatx4 acc[2][3];
#pragma unroll
        for (int i = 0; i < 2; ++i)
#pragma unroll
            for (int j = 0; j < 3; ++j) acc[i][j] = (floatx4){0.f, 0.f, 0.f, 0.f};

        const int xr = tid >> 3, xsc = tid & 7;
        const int xcg = xsc ^ (xr & 7);
        const float* xaddr = x + (row0 + xr) * D_MODEL + xcg * 8;

        float4 xc[2];
        half8  wc[6];
        auto loadx = [&](int k0) {
            xc[0] = *(const float4*)(xaddr + k0);
            xc[1] = *(const float4*)(xaddr + k0 + 4);
        };
        auto loadw = [&](int k0) {
#pragma unroll
            for (int i = 0; i < 6; ++i) {
                int idx = i * 256 + tid;
                int r = idx >> 3, sc = idx & 7;
                int cg = sc ^ (r & 7);
                wc[i] = *(const half8*)(Wt + (size_t)r * D_MODEL + k0 + cg * 8);
            }
        };

        loadx(0);
        loadw(0);
        for (int it = 0; it < 12; ++it) {
            half8 xh = (half8){(half_t)xc[0].x, (half_t)xc[0].y, (half_t)xc[0].z, (half_t)xc[0].w,
                               (half_t)xc[1].x, (half_t)xc[1].y, (half_t)xc[1].z, (half_t)xc[1].w};
            *(half8*)&sm.proj.xs[tid * 8] = xh;
#pragma unroll
            for (int i = 0; i < 6; ++i)
                *(half8*)&sm.proj.wt[(i * 256 + tid) * 8] = wc[i];
            __syncthreads();                  // tile staged
            int kn = (it + 1 < 12) ? (it + 1) * 64 : 0;
            loadx(kn);                        // prefetch, covered by MFMAs
            loadw(kn);
#pragma unroll
            for (int kst = 0; kst < 2; ++kst) {
                half8 af[2];
#pragma unroll
                for (int mt = 0; mt < 2; ++mt) {
                    int r = mt * 16 + l15;
                    int slot = (kst * 4 + quad) ^ (r & 7);
                    af[mt] = *(const half8*)&sm.proj.xs[r * 64 + slot * 8];
                }
#pragma unroll
                for (int nt = 0; nt < 3; ++nt) {
                    int r = w * 48 + nt * 16 + l15;
                    int slot = (kst * 4 + quad) ^ (r & 7);
                    half8 bf = *(const half8*)&sm.proj.wt[r * 64 + slot * 8];
#pragma unroll
                    for (int mt = 0; mt < 2; ++mt)
                        acc[mt][nt] = __builtin_amdgcn_mfma_f32_16x16x32_f16(
                            af[mt], bf, acc[mt][nt], 0, 0, 0);
                }
            }
            __syncthreads();                  // reads done before next stage
        }

#pragma unroll
        for (int nt = 0; nt < 3; ++nt) {
            int nbase = w * 48 + nt * 16;
            int mm = nbase >> 6;
            int h = (nbase + l15) & 63;
            const float* bias = (mm == 0) ? bq : ((mm == 1) ? bk : bv);
            float bval = bias[h];
#pragma unroll
            for (int mt = 0; mt < 2; ++mt)
#pragma unroll
                for (int r = 0; r < 4; ++r) {
                    long R = row0 + mt * 16 + quad * 4 + r;
                    half_t hv = (half_t)(acc[mt][nt][r] + bval);
                    if (mm == 0)      Qh[R * HS + h] = hv;
                    else if (mm == 1) Kh[R * HS + h] = hv;
                    else {
                        long bb = R >> 11, s = R & 2047;
                        Vt[(bb * HS + h) * SEQ + s] = hv;
                    }
                }
        }
    }

    __threadfence();
    grid.sync();

    // ================= Phase 2: flash attention =================
    {
        const int kh = bid >> 6;
        const int b = (bid >> 3) & 7;
        const int qblk = bid & 7;
        const int q0 = qblk * 256 + w * 64;
        const int kk_begin = kh * KCHUNK;

        const half_t* Kb = Kh + (size_t)b * SEQ * HS;
        const half_t* Vb = Vt + (size_t)b * HS * SEQ;

        half8 qf[4][2];
#pragma unroll
        for (int mt = 0; mt < 4; ++mt)
#pragma unroll
            for (int kst = 0; kst < 2; ++kst) {
                half8 q = *(const half8*)(Qh + ((size_t)b * SEQ + q0 + mt * 16 + l15) * HS
                                          + kst * 32 + quad * 8);
#pragma unroll
                for (int j = 0; j < 8; ++j) q[j] = q[j] * (half_t)SCALE;
                qf[mt][kst] = q;
            }

        floatx4 oacc[4][4];
        float lsum[4][4];
#pragma unroll
        for (int mt = 0; mt < 4; ++mt) {
#pragma unroll
            for (int nt = 0; nt < 4; ++nt) oacc[mt][nt] = (floatx4){0.f, 0.f, 0.f, 0.f};
#pragma unroll
            for (int r = 0; r < 4; ++r) lsum[mt][r] = 0.f;
        }

        half8 kc[2], vc[2];
        auto loadkv = [&](int kk0) {
#pragma unroll
            for (int i = 0; i < 2; ++i) {
                int idx = i * 256 + tid;
                int r = idx >> 3, sc = idx & 7;
                int cg = sc ^ (r & 7);
                kc[i] = *(const half8*)(Kb + (size_t)(kk0 + r) * HS + cg * 8);
                vc[i] = *(const half8*)(Vb + (size_t)r * SEQ + kk0 + cg * 8);
            }
        };

        loadkv(kk_begin);
        for (int it = 0; it < KCHUNK / 64; ++it) {
#pragma unroll
            for (int i = 0; i < 2; ++i) {
                int idx = i * 256 + tid;
                *(half8*)&sm.attn.ks[idx * 8] = kc[i];
                *(half8*)&sm.attn.vs[idx * 8] = vc[i];
            }
            __syncthreads();                  // tile staged
            int kkn = (it + 1 < KCHUNK / 64) ? kk_begin + (it + 1) * 64 : kk_begin;
            loadkv(kkn);                      // prefetch, covered by compute

#pragma unroll
            for (int h2 = 0; h2 < 2; ++h2) {
                floatx4 sacc[2][4];
#pragma unroll
                for (int mtl = 0; mtl < 2; ++mtl)
#pragma unroll
                    for (int nt = 0; nt < 4; ++nt) sacc[mtl][nt] = (floatx4){0.f, 0.f, 0.f, 0.f};
#pragma unroll
                for (int nt = 0; nt < 4; ++nt)
#pragma unroll
                    for (int kst = 0; kst < 2; ++kst) {
                        int r = nt * 16 + l15;
                        int slot = (kst * 4 + quad) ^ (r & 7);
                        half8 kf = *(const half8*)&sm.attn.ks[r * 64 + slot * 8];
#pragma unroll
                        for (int mtl = 0; mtl < 2; ++mtl)
                            sacc[mtl][nt] = __builtin_amdgcn_mfma_f32_16x16x32_f16(
                                qf[h2 * 2 + mtl][kst], kf, sacc[mtl][nt], 0, 0, 0);
                    }

#pragma unroll
                for (int mtl = 0; mtl < 2; ++mtl) {
                    int mt = h2 * 2 + mtl;
#pragma unroll
                    for (int nt = 0; nt < 4; ++nt)
#pragma unroll
                        for (int r = 0; r < 4; ++r) {
                            float pv = __expf(sacc[mtl][nt][r]);
                            lsum[mt][r] += pv;
                            sm.attn.ps[w][quad * 4 + r][nt * 16 + l15] = (half_t)pv;
                        }
                    half8 pfr[2];
#pragma unroll
                    for (int kst = 0; kst < 2; ++kst)
                        pfr[kst] = *(const half8*)&sm.attn.ps[w][l15][kst * 32 + quad * 8];
#pragma unroll
                    for (int nt = 0; nt < 4; ++nt)
#pragma unroll
                        for (int kst = 0; kst < 2; ++kst) {
                            int r = nt * 16 + l15;
                            int slot = (kst * 4 + quad) ^ (r & 7);
                            half8 vf = *(const half8*)&sm.attn.vs[r * 64 + slot * 8];
                            oacc[mt][nt] = __builtin_amdgcn_mfma_f32_16x16x32_f16(
                                pfr[kst], vf, oacc[mt][nt], 0, 0, 0);
                        }
                }
            }
            __syncthreads();                  // reads done before next stage
        }

#pragma unroll
        for (int mt = 0; mt < 4; ++mt)
#pragma unroll
            for (int r = 0; r < 4; ++r) {
                float s = lsum[mt][r];
                s += __shfl_xor(s, 1);
                s += __shfl_xor(s, 2);
                s += __shfl_xor(s, 4);
                s += __shfl_xor(s, 8);
                lsum[mt][r] = s;
            }

        size_t obase = ((size_t)kh * BATCH + b) * SEQ * HS;
#pragma unroll
        for (int mt = 0; mt < 4; ++mt)
#pragma unroll
            for (int nt = 0; nt < 4; ++nt)
#pragma unroll
                for (int r = 0; r < 4; ++r) {
                    int row = q0 + mt * 16 + quad * 4 + r;
                    Opart[obase + (size_t)row * HS + nt * 16 + l15] = (half_t)oacc[mt][nt][r];
                }
        if (l15 == 0) {
#pragma unroll
            for (int mt = 0; mt < 4; ++mt)
#pragma unroll
                for (int r = 0; r < 4; ++r) {
                    int row = q0 + mt * 16 + quad * 4 + r;
                    lpart[((size_t)kh * BATCH + b) * SEQ + row] = lsum[mt][r];
                }
        }
    }

    __threadfence();
    grid.sync();

    // ================= Phase 3: combine =================
    {
        const size_t NT = (size_t)BATCH * SEQ * HS;
        const size_t BS = (size_t)BATCH * SEQ;
        size_t e0 = ((size_t)bid * 256 + tid) * 8;
        size_t row = e0 / HS;
        float o[8] = {0, 0, 0, 0, 0, 0, 0, 0};
        float l = 0.f;
#pragma unroll
        for (int i = 0; i < KSPLIT; ++i) {
            half8 oi = *(const half8*)(Opart + (size_t)i * NT + e0);
#pragma unroll
            for (int j = 0; j < 8; ++j) o[j] += (float)oi[j];
            l += lpart[(size_t)i * BS + row];
        }
        float inv = 1.f / l;
        float4 a = {o[0] * inv, o[1] * inv, o[2] * inv, o[3] * inv};
        float4 c = {o[4] * inv, o[5] * inv, o[6] * inv, o[7] * inv};
        *(float4*)(out + e0) = a;
        *(float4*)(out + e0 + 4) = c;
    }
}

// ===============================================================
// Fallback path (R8-proven separate kernels, bitwise-equal math)
// ===============================================================
__global__ __launch_bounds__(256)
void proj_kernel(const float* __restrict__ x, const half_t* __restrict__ Wt,
                 const float* __restrict__ bq, const float* __restrict__ bk,
                 const float* __restrict__ bv,
                 half_t* __restrict__ Qh, half_t* __restrict__ Kh,
                 half_t* __restrict__ Vt)
{
    __shared__ __align__(16) half_t xs[32 * 64];
    __shared__ __align__(16) half_t wt[192 * 64];

    const int tid = threadIdx.x;
    const int w = tid >> 6;
    const int lane = tid & 63;
    const int l15 = lane & 15;
    const int quad = lane >> 4;
    const long row0 = (long)blockIdx.x * 32;

    floatx4 acc[2][3];
#pragma unroll
    for (int i = 0; i < 2; ++i)
#pragma unroll
        for (int j = 0; j < 3; ++j) acc[i][j] = (floatx4){0.f, 0.f, 0.f, 0.f};

    const int xr = tid >> 3, xsc = tid & 7;
    const int xcg = xsc ^ (xr & 7);
    const float* xaddr = x + (row0 + xr) * D_MODEL + xcg * 8;

    float4 xc[2];
    half8  wc[6];
    auto loadx = [&](int k0) {
        xc[0] = *(const float4*)(xaddr + k0);
        xc[1] = *(const float4*)(xaddr + k0 + 4);
    };
    auto loadw = [&](int k0) {
#pragma unroll
        for (int i = 0; i < 6; ++i) {
            int idx = i * 256 + tid;
            int r = idx >> 3, sc = idx & 7;
            int cg = sc ^ (r & 7);
            wc[i] = *(const half8*)(Wt + (size_t)r * D_MODEL + k0 + cg * 8);
        }
    };

    loadx(0);
    loadw(0);
    for (int it = 0; it < 12; ++it) {
        half8 xh = (half8){(half_t)xc[0].x, (half_t)xc[0].y, (half_t)xc[0].z, (half_t)xc[0].w,
                           (half_t)xc[1].x, (half_t)xc[1].y, (half_t)xc[1].z, (half_t)xc[1].w};
        *(half8*)&xs[tid * 8] = xh;
#pragma unroll
        for (int i = 0; i < 6; ++i)
            *(half8*)&wt[(i * 256 + tid) * 8] = wc[i];
        __syncthreads();
        int kn = (it + 1 < 12) ? (it + 1) * 64 : 0;
        loadx(kn);
        loadw(kn);
#pragma unroll
        for (int kst = 0; kst < 2; ++kst) {
            half8 af[2];
#pragma unroll
            for (int mt = 0; mt < 2; ++mt) {
                int r = mt * 16 + l15;
                int slot = (kst * 4 + quad) ^ (r & 7);
                af[mt] = *(const half8*)&xs[r * 64 + slot * 8];
            }
#pragma unroll
            for (int nt = 0; nt < 3; ++nt) {
                int r = w * 48 + nt * 16 + l15;
                int slot = (kst * 4 + quad) ^ (r & 7);
                half8 bf = *(const half8*)&wt[r * 64 + slot * 8];
#pragma unroll
                for (int mt = 0; mt < 2; ++mt)
                    acc[mt][nt] = __builtin_amdgcn_mfma_f32_16x16x32_f16(
                        af[mt], bf, acc[mt][nt], 0, 0, 0);
            }
        }
        __syncthreads();
    }

#pragma unroll
    for (int nt = 0; nt < 3; ++nt) {
        int nbase = w * 48 + nt * 16;
        int mm = nbase >> 6;
        int h = (nbase + l15) & 63;
        const float* bias = (mm == 0) ? bq : ((mm == 1) ? bk : bv);
        float bval = bias[h];
#pragma unroll
        for (int mt = 0; mt < 2; ++mt)
#pragma unroll
            for (int r = 0; r < 4; ++r) {
                long R = row0 + mt * 16 + quad * 4 + r;
                half_t hv = (half_t)(acc[mt][nt][r] + bval);
                if (mm == 0)      Qh[R * HS + h] = hv;
                else if (mm == 1) Kh[R * HS + h] = hv;
                else {
                    long bb = R >> 11, s = R & 2047;
                    Vt[(bb * HS + h) * SEQ + s] = hv;
                }
            }
    }
}

__global__ __launch_bounds__(256)
void attn_kernel(const half_t* __restrict__ Qh, const half_t* __restrict__ Kh,
                 const half_t* __restrict__ Vt,
                 half_t* __restrict__ Opart, float* __restrict__ lpart,
                 int kchunk)
{
    __shared__ __align__(16) half_t ks[64 * 64];
    __shared__ __align__(16) half_t vs[64 * 64];
    __shared__ __align__(16) half_t ps[4][16][72];

    const int tid = threadIdx.x;
    const int w = tid >> 6;
    const int lane = tid & 63;
    const int l15 = lane & 15;
    const int quad = lane >> 4;
    const int b = blockIdx.y;
    const int q0 = blockIdx.x * 256 + w * 64;
    const int kh = blockIdx.z;
    const int kk_begin = kh * kchunk;
    const int nk = kchunk >> 6;

    const half_t* Kb = Kh + (size_t)b * SEQ * HS;
    const half_t* Vb = Vt + (size_t)b * HS * SEQ;

    half8 qf[4][2];
#pragma unroll
    for (int mt = 0; mt < 4; ++mt)
#pragma unroll
        for (int kst = 0; kst < 2; ++kst) {
            half8 q = *(const half8*)(Qh + ((size_t)b * SEQ + q0 + mt * 16 + l15) * HS
                                      + kst * 32 + quad * 8);
#pragma unroll
            for (int j = 0; j < 8; ++j) q[j] = q[j] * (half_t)SCALE;
            qf[mt][kst] = q;
        }

    floatx4 oacc[4][4];
    float lsum[4][4];
#pragma unroll
    for (int mt = 0; mt < 4; ++mt) {
#pragma unroll
        for (int nt = 0; nt < 4; ++nt) oacc[mt][nt] = (floatx4){0.f, 0.f, 0.f, 0.f};
#pragma unroll
        for (int r = 0; r < 4; ++r) lsum[mt][r] = 0.f;
    }

    half8 kc[2], vc[2];
    auto loadkv = [&](int kk0) {
#pragma unroll
        for (int i = 0; i < 2; ++i) {
            int idx = i * 256 + tid;
            int r = idx >> 3, sc = idx & 7;
            int cg = sc ^ (r & 7);
            kc[i] = *(const half8*)(Kb + (size_t)(kk0 + r) * HS + cg * 8);
            vc[i] = *(const half8*)(Vb + (size_t)r * SEQ + kk0 + cg * 8);
        }
    };

    loadkv(kk_begin);
    for (int it = 0; it < nk; ++it) {
#pragma unroll
        for (int i = 0; i < 2; ++i) {
            int idx = i * 256 + tid;
            *(half8*)&ks[idx * 8] = kc[i];
            *(half8*)&vs[idx * 8] = vc[i];
        }
        __syncthreads();
        int kkn = (it + 1 < nk) ? kk_begin + (it + 1) * 64 : kk_begin;
        loadkv(kkn);

#pragma unroll
        for (int h2 = 0; h2 < 2; ++h2) {
            floatx4 sacc[2][4];
#pragma unroll
            for (int mtl = 0; mtl < 2; ++mtl)
#pragma unroll
                for (int nt = 0; nt < 4; ++nt) sacc[mtl][nt] = (floatx4){0.f, 0.f, 0.f, 0.f};
#pragma unroll
            for (int nt = 0; nt < 4; ++nt)
#pragma unroll
                for (int kst = 0; kst < 2; ++kst) {
                    int r = nt * 16 + l15;
                    int slot = (kst * 4 + quad) ^ (r & 7);
                    half8 kf = *(const half8*)&ks[r * 64 + slot * 8];
#pragma unroll
                    for (int mtl = 0; mtl < 2; ++mtl)
                        sacc[mtl][nt] = __builtin_amdgcn_mfma_f32_16x16x32_f16(
                            qf[h2 * 2 + mtl][kst], kf, sacc[mtl][nt], 0, 0, 0);
                }

#pragma unroll
            for (int mtl = 0; mtl < 2; ++mtl) {
                int mt = h2 * 2 + mtl;
#pragma unroll
                for (int nt = 0; nt < 4; ++nt)
#pragma unroll
                    for (int r = 0; r < 4; ++r) {
                        float pv = __expf(sacc[mtl][nt][r]);
                        lsum[mt][r] += pv;
                        ps[w][quad * 4 + r][nt * 16 + l15] = (half_t)pv;
                    }
                half8 pfr[2];
#pragma unroll
                for (int kst = 0; kst < 2; ++kst)
                    pfr[kst] = *(const half8*)&ps[w][l15][kst * 32 + quad * 8];
#pragma unroll
                for (int nt = 0; nt < 4; ++nt)
#pragma unroll
                    for (int kst = 0; kst < 2; ++kst) {
                        int r = nt * 16 + l15;
                        int slot = (kst * 4 + quad) ^ (r & 7);
                        half8 vf = *(const half8*)&vs[r * 64 + slot * 8];
                        oacc[mt][nt] = __builtin_amdgcn_mfma_f32_16x16x32_f16(
                            pfr[kst], vf, oacc[mt][nt], 0, 0, 0);
                    }
            }
        }
        __syncthreads();
    }

#pragma unroll
    for (int mt = 0; mt < 4; ++mt)
#pragma unroll
        for (int r = 0; r < 4; ++r) {
            float s = lsum[mt][r];
            s += __shfl_xor(s, 1);
            s += __shfl_xor(s, 2);
            s += __shfl_xor(s, 4);
            s += __shfl_xor(s, 8);
            lsum[mt][r] = s;
        }

    size_t obase = ((size_t)kh * BATCH + b) * SEQ * HS;
#pragma unroll
    for (int mt = 0; mt < 4; ++mt)
#pragma unroll
        for (int nt = 0; nt < 4; ++nt)
#pragma unroll
            for (int r = 0; r < 4; ++r) {
                int row = q0 + mt * 16 + quad * 4 + r;
                Opart[obase + (size_t)row * HS + nt * 16 + l15] = (half_t)oacc[mt][nt][r];
            }
    if (l15 == 0) {
#pragma unroll
        for (int mt = 0; mt < 4; ++mt)
#pragma unroll
            for (int r = 0; r < 4; ++r) {
                int row = q0 + mt * 16 + quad * 4 + r;
                lpart[((size_t)kh * BATCH + b) * SEQ + row] = lsum[mt][r];
            }
    }
}

__global__ __launch_bounds__(256)
void combine_kernel(const half_t* __restrict__ Opart, const float* __restrict__ lpart,
                    float* __restrict__ out, int nsplit)
{
    const size_t NT = (size_t)BATCH * SEQ * HS;
    const size_t BS = (size_t)BATCH * SEQ;
    size_t e0 = ((size_t)blockIdx.x * 256 + threadIdx.x) * 8;
    size_t row = e0 / HS;
    float o[8] = {0, 0, 0, 0, 0, 0, 0, 0};
    float l = 0.f;
    for (int i = 0; i < nsplit; ++i) {
        half8 oi = *(const half8*)(Opart + (size_t)i * NT + e0);
#pragma unroll
        for (int j = 0; j < 8; ++j) o[j] += (float)oi[j];
        l += lpart[(size_t)i * BS + row];
    }
    float inv = 1.f / l;
    float4 a = {o[0] * inv, o[1] * inv, o[2] * inv, o[3] * inv};
    float4 c = {o[4] * inv, o[5] * inv, o[6] * inv, o[7] * inv};
    *(float4*)(out + e0) = a;
    *(float4*)(out + e0 + 4) = c;
}

extern "C" void kernel_launch(void* const* d_in, const int* in_sizes, int n_in,
                              void* d_out, int out_size, void* d_ws, size_t ws_size,
                              hipStream_t stream) {
    const float* x  = (const float*)d_in[0];
    const float* Wq = (const float*)d_in[1];
    const float* bq = (const float*)d_in[2];
    const float* Wk = (const float*)d_in[3];
    const float* bk = (const float*)d_in[4];
    const float* Wv = (const float*)d_in[5];
    const float* bv = (const float*)d_in[6];
    float* out = (float*)d_out;

    const size_t per = (size_t)BATCH * SEQ * HS;      // 1,048,576 elements
    half_t* Qh = (half_t*)d_ws;
    half_t* Kh = Qh + per;
    half_t* Vt = Kh + per;
    half_t* Wt = Vt + per;                            // 147,456 halfs
    half_t* Opart = Wt + 3 * HS * D_MODEL;
    float*  lpart = (float*)(Opart + (size_t)KSPLIT * per);   // ~23 MB total

    wconv_kernel<<<dim3(3 * HS), dim3(256), 0, stream>>>(Wq, Wk, Wv, Wt);

    void* args[] = {(void*)&x, (void*)&Wt, (void*)&bq, (void*)&bk, (void*)&bv,
                    (void*)&out, (void*)&Qh, (void*)&Kh, (void*)&Vt,
                    (void*)&Opart, (void*)&lpart};
    hipError_t err = hipLaunchCooperativeKernel((void*)fused_kernel, dim3(512),
                                                dim3(256), args, 0, stream);
    if (err != hipSuccess) {
        // deterministic fallback: separate kernels, bitwise-equal math
        proj_kernel<<<dim3(BATCH * SEQ / 32), dim3(256), 0, stream>>>(
            x, Wt, bq, bk, bv, Qh, Kh, Vt);
        attn_kernel<<<dim3(SEQ / 256, BATCH, KSPLIT), dim3(256), 0, stream>>>(
            Qh, Kh, Vt, Opart, lpart, KCHUNK);
        combine_kernel<<<dim3((BATCH * SEQ * HS) / (256 * 8)), dim3(256), 0, stream>>>(
            Opart, lpart, out, KSPLIT);
    }
}

// Round 11
// 141.766 us; speedup vs baseline: 2.6820x; 2.6820x over previous
//
#include <hip/hip_runtime.h>
#include <math.h>

#define D_MODEL 768
#define HS 64
#define BATCH 8
#define SEQ 2048
#define SCALE 0.125f
#define KSPLIT 8
#define KCHUNK (SEQ / KSPLIT)   // 256

typedef _Float16 half_t;
typedef __attribute__((ext_vector_type(8))) _Float16 half8;
typedef __attribute__((ext_vector_type(4))) float floatx4;

// async global->LDS, 16B per lane, lane-linear LDS destination
typedef const __attribute__((address_space(1))) void gas_void;
typedef __attribute__((address_space(3))) void las_void;
__device__ __forceinline__ void gl_lds16(const void* g, void* l) {
    __builtin_amdgcn_global_load_lds((gas_void*)g, (las_void*)l, 16, 0, 0);
}
// drain ALL outstanding counters (vmcnt incl. global_load_lds, lgkmcnt)
__device__ __forceinline__ void waitcnt_all() {
    __builtin_amdgcn_s_waitcnt(0);
}

// ---------------------------------------------------------------
// Kernel 1: W fp32 [D][H] x3 -> Wt fp16 [3*H][D]
// ---------------------------------------------------------------
__global__ __launch_bounds__(256)
void wconv_kernel(const float* __restrict__ Wq, const float* __restrict__ Wk,
                  const float* __restrict__ Wv, half_t* __restrict__ Wt)
{
    int m = blockIdx.x >> 6;
    int h = blockIdx.x & 63;
    const float* W = (m == 0) ? Wq : ((m == 1) ? Wk : Wv);
    half_t* dst = Wt + (size_t)blockIdx.x * D_MODEL;
    for (int k = threadIdx.x; k < D_MODEL; k += 256)
        dst[k] = (half_t)W[(size_t)k * HS + h];
}

// ---------------------------------------------------------------
// Kernel 2: QKV projection, m97-style two-barrier global_load_lds
// staging with explicit waitcnt (race-proof). XOR-swizzled tiles.
// Block 256 = 4 waves, tile M=32 x N=192, BK=64. Grid 512.
// ---------------------------------------------------------------
__global__ __launch_bounds__(256)
void proj_kernel(const float* __restrict__ x, const half_t* __restrict__ Wt,
                 const float* __restrict__ bq, const float* __restrict__ bk,
                 const float* __restrict__ bv,
                 half_t* __restrict__ Qh, half_t* __restrict__ Kh,
                 half_t* __restrict__ Vt)
{
    // xs: 32 rows x 16 fp32-chunks (chunk c of row r at slot c^(r&15))
    __shared__ __align__(16) float  xs[32 * 64];       // 8 KB
    // wt: 192 rows x 8 half8-chunks (chunk c of row r at slot c^(r&7))
    __shared__ __align__(16) half_t wt[192 * 64];      // 24 KB

    const int tid = threadIdx.x;
    const int w = tid >> 6;
    const int lane = tid & 63;
    const int l15 = lane & 15;
    const int quad = lane >> 4;
    const long row0 = (long)blockIdx.x * 32;

    floatx4 acc[2][3];
#pragma unroll
    for (int i = 0; i < 2; ++i)
#pragma unroll
        for (int j = 0; j < 3; ++j) acc[i][j] = (floatx4){0.f, 0.f, 0.f, 0.f};

    for (int k0 = 0; k0 < D_MODEL; k0 += 64) {
        __syncthreads();   // WAR: previous tile's readers done
        // stage x: 512 fp32-chunks (2/thread)
#pragma unroll
        for (int i = 0; i < 2; ++i) {
            int idx = i * 256 + tid;
            int r = idx >> 4, sc = idx & 15;
            int cg = sc ^ (r & 15);
            gl_lds16(x + (row0 + r) * D_MODEL + k0 + cg * 4, xs + idx * 4);
        }
        // stage Wt: 1536 half8-chunks (6/thread)
#pragma unroll
        for (int i = 0; i < 6; ++i) {
            int idx = i * 256 + tid;
            int r = idx >> 3, sc = idx & 7;
            int cg = sc ^ (r & 7);
            gl_lds16(Wt + (size_t)r * D_MODEL + k0 + cg * 8, wt + idx * 8);
        }
        waitcnt_all();     // gl_lds writes landed (vmcnt-tracked!)
        __syncthreads();   // tiles visible to all waves

#pragma unroll
        for (int kst = 0; kst < 2; ++kst) {
            half8 af[2];
#pragma unroll
            for (int mt = 0; mt < 2; ++mt) {
                int r = mt * 16 + l15;
                int c0 = kst * 8 + quad * 2;
                float4 f0 = *(const float4*)&xs[r * 64 + (c0 ^ l15) * 4];
                float4 f1 = *(const float4*)&xs[r * 64 + ((c0 + 1) ^ l15) * 4];
                af[mt] = (half8){(half_t)f0.x, (half_t)f0.y, (half_t)f0.z, (half_t)f0.w,
                                 (half_t)f1.x, (half_t)f1.y, (half_t)f1.z, (half_t)f1.w};
            }
#pragma unroll
            for (int nt = 0; nt < 3; ++nt) {
                int r = w * 48 + nt * 16 + l15;
                int slot = (kst * 4 + quad) ^ (r & 7);
                half8 bf = *(const half8*)&wt[r * 64 + slot * 8];
#pragma unroll
                for (int mt = 0; mt < 2; ++mt)
                    acc[mt][nt] = __builtin_amdgcn_mfma_f32_16x16x32_f16(
                        af[mt], bf, acc[mt][nt], 0, 0, 0);
            }
        }
    }

    // epilogue: bias + fp16 store (n-tiles never straddle 64-boundaries)
#pragma unroll
    for (int nt = 0; nt < 3; ++nt) {
        int nbase = w * 48 + nt * 16;
        int mm = nbase >> 6;
        int h = (nbase + l15) & 63;
        const float* bias = (mm == 0) ? bq : ((mm == 1) ? bk : bv);
        float bval = bias[h];
#pragma unroll
        for (int mt = 0; mt < 2; ++mt)
#pragma unroll
            for (int r = 0; r < 4; ++r) {
                long R = row0 + mt * 16 + quad * 4 + r;
                half_t hv = (half_t)(acc[mt][nt][r] + bval);
                if (mm == 0)      Qh[R * HS + h] = hv;
                else if (mm == 1) Kh[R * HS + h] = hv;
                else {
                    long bb = R >> 11, s = R & 2047;
                    Vt[(bb * HS + h) * SEQ + s] = hv;
                }
            }
    }
}

// ---------------------------------------------------------------
// Kernel 3: flash attention, 64 q/wave (block = 256 q), m97-style
// gl_lds staging + explicit waitcnt, V-frags hoisted to registers
// once per k-tile. ps = per-wave 16-row buffer, 4 sequential mtl
// passes (validated in R10 phase 2). No-max softmax. ksplit=8.
// ---------------------------------------------------------------
__global__ __launch_bounds__(256)
void attn_kernel(const half_t* __restrict__ Qh, const half_t* __restrict__ Kh,
                 const half_t* __restrict__ Vt,
                 half_t* __restrict__ Opart, float* __restrict__ lpart)
{
    __shared__ __align__(16) half_t ks[64 * 64];      // 8 KB [kk][h] swizzled
    __shared__ __align__(16) half_t vs[64 * 64];      // 8 KB [h][kk] swizzled
    __shared__ __align__(16) half_t ps[4][16][72];    // 9 KB per-wave P

    const int tid = threadIdx.x;
    const int w = tid >> 6;
    const int lane = tid & 63;
    const int l15 = lane & 15;
    const int quad = lane >> 4;
    const int b = blockIdx.y;
    const int q0 = blockIdx.x * 256 + w * 64;
    const int kh = blockIdx.z;
    const int kk_begin = kh * KCHUNK;

    const half_t* Kb = Kh + (size_t)b * SEQ * HS;
    const half_t* Vb = Vt + (size_t)b * HS * SEQ;

    half8 qf[4][2];
#pragma unroll
    for (int mt = 0; mt < 4; ++mt)
#pragma unroll
        for (int kst = 0; kst < 2; ++kst) {
            half8 q = *(const half8*)(Qh + ((size_t)b * SEQ + q0 + mt * 16 + l15) * HS
                                      + kst * 32 + quad * 8);
#pragma unroll
            for (int j = 0; j < 8; ++j) q[j] = q[j] * (half_t)SCALE;
            qf[mt][kst] = q;
        }

    floatx4 oacc[4][4];
    float lsum[4][4];
#pragma unroll
    for (int mt = 0; mt < 4; ++mt) {
#pragma unroll
        for (int nt = 0; nt < 4; ++nt) oacc[mt][nt] = (floatx4){0.f, 0.f, 0.f, 0.f};
#pragma unroll
        for (int r = 0; r < 4; ++r) lsum[mt][r] = 0.f;
    }

    for (int it = 0; it < KCHUNK / 64; ++it) {
        const int kk0 = kk_begin + it * 64;
        __syncthreads();   // WAR: previous tile's readers done
        // stage K + V^T: 512+512 half8-chunks (2+2 gl_lds/thread)
#pragma unroll
        for (int i = 0; i < 2; ++i) {
            int idx = i * 256 + tid;
            int r = idx >> 3, sc = idx & 7;
            int cg = sc ^ (r & 7);
            gl_lds16(Kb + (size_t)(kk0 + r) * HS + cg * 8, ks + idx * 8);
            gl_lds16(Vb + (size_t)r * SEQ + kk0 + cg * 8, vs + idx * 8);
        }
        waitcnt_all();     // async LDS writes landed
        __syncthreads();   // tiles visible

        // V-fragments into registers once per tile (reused by 4 mtl passes)
        half8 vf[4][2];
#pragma unroll
        for (int nt = 0; nt < 4; ++nt)
#pragma unroll
            for (int kst = 0; kst < 2; ++kst) {
                int r = nt * 16 + l15;
                int slot = (kst * 4 + quad) ^ (r & 7);
                vf[nt][kst] = *(const half8*)&vs[r * 64 + slot * 8];
            }

#pragma unroll
        for (int h2 = 0; h2 < 2; ++h2) {
            floatx4 sacc[2][4];
#pragma unroll
            for (int mtl = 0; mtl < 2; ++mtl)
#pragma unroll
                for (int nt = 0; nt < 4; ++nt) sacc[mtl][nt] = (floatx4){0.f, 0.f, 0.f, 0.f};
#pragma unroll
            for (int nt = 0; nt < 4; ++nt)
#pragma unroll
                for (int kst = 0; kst < 2; ++kst) {
                    int r = nt * 16 + l15;
                    int slot = (kst * 4 + quad) ^ (r & 7);
                    half8 kf = *(const half8*)&ks[r * 64 + slot * 8];
#pragma unroll
                    for (int mtl = 0; mtl < 2; ++mtl)
                        sacc[mtl][nt] = __builtin_amdgcn_mfma_f32_16x16x32_f16(
                            qf[h2 * 2 + mtl][kst], kf, sacc[mtl][nt], 0, 0, 0);
                }

#pragma unroll
            for (int mtl = 0; mtl < 2; ++mtl) {
                int mt = h2 * 2 + mtl;
#pragma unroll
                for (int nt = 0; nt < 4; ++nt)
#pragma unroll
                    for (int r = 0; r < 4; ++r) {
                        float pv = __expf(sacc[mtl][nt][r]);
                        lsum[mt][r] += pv;
                        ps[w][quad * 4 + r][nt * 16 + l15] = (half_t)pv;
                    }
                half8 pfr[2];
#pragma unroll
                for (int kst = 0; kst < 2; ++kst)
                    pfr[kst] = *(const half8*)&ps[w][l15][kst * 32 + quad * 8];
#pragma unroll
                for (int nt = 0; nt < 4; ++nt)
#pragma unroll
                    for (int kst = 0; kst < 2; ++kst)
                        oacc[mt][nt] = __builtin_amdgcn_mfma_f32_16x16x32_f16(
                            pfr[kst], vf[nt][kst], oacc[mt][nt], 0, 0, 0);
            }
        }
    }

    // reduce l across the 16 column-lanes of each quad
#pragma unroll
    for (int mt = 0; mt < 4; ++mt)
#pragma unroll
        for (int r = 0; r < 4; ++r) {
            float s = lsum[mt][r];
            s += __shfl_xor(s, 1);
            s += __shfl_xor(s, 2);
            s += __shfl_xor(s, 4);
            s += __shfl_xor(s, 8);
            lsum[mt][r] = s;
        }

    size_t obase = ((size_t)kh * BATCH + b) * SEQ * HS;
#pragma unroll
    for (int mt = 0; mt < 4; ++mt)
#pragma unroll
        for (int nt = 0; nt < 4; ++nt)
#pragma unroll
            for (int r = 0; r < 4; ++r) {
                int row = q0 + mt * 16 + quad * 4 + r;
                Opart[obase + (size_t)row * HS + nt * 16 + l15] = (half_t)oacc[mt][nt][r];
            }
    if (l15 == 0) {
#pragma unroll
        for (int mt = 0; mt < 4; ++mt)
#pragma unroll
            for (int r = 0; r < 4; ++r) {
                int row = q0 + mt * 16 + quad * 4 + r;
                lpart[((size_t)kh * BATCH + b) * SEQ + row] = lsum[mt][r];
            }
    }
}

// ---------------------------------------------------------------
// Kernel 4: combine KSPLIT partials: out = sum(O_i) / sum(l_i)
// ---------------------------------------------------------------
__global__ __launch_bounds__(256)
void combine_kernel(const half_t* __restrict__ Opart, const float* __restrict__ lpart,
                    float* __restrict__ out)
{
    const size_t NT = (size_t)BATCH * SEQ * HS;
    const size_t BS = (size_t)BATCH * SEQ;
    size_t e0 = ((size_t)blockIdx.x * 256 + threadIdx.x) * 8;
    size_t row = e0 / HS;
    float o[8] = {0, 0, 0, 0, 0, 0, 0, 0};
    float l = 0.f;
#pragma unroll
    for (int i = 0; i < KSPLIT; ++i) {
        half8 oi = *(const half8*)(Opart + (size_t)i * NT + e0);
#pragma unroll
        for (int j = 0; j < 8; ++j) o[j] += (float)oi[j];
        l += lpart[(size_t)i * BS + row];
    }
    float inv = 1.f / l;
    float4 a = {o[0] * inv, o[1] * inv, o[2] * inv, o[3] * inv};
    float4 c = {o[4] * inv, o[5] * inv, o[6] * inv, o[7] * inv};
    *(float4*)(out + e0) = a;
    *(float4*)(out + e0 + 4) = c;
}

extern "C" void kernel_launch(void* const* d_in, const int* in_sizes, int n_in,
                              void* d_out, int out_size, void* d_ws, size_t ws_size,
                              hipStream_t stream) {
    const float* x  = (const float*)d_in[0];
    const float* Wq = (const float*)d_in[1];
    const float* bq = (const float*)d_in[2];
    const float* Wk = (const float*)d_in[3];
    const float* bk = (const float*)d_in[4];
    const float* Wv = (const float*)d_in[5];
    const float* bv = (const float*)d_in[6];
    float* out = (float*)d_out;

    const size_t per = (size_t)BATCH * SEQ * HS;      // 1,048,576 elements
    half_t* Qh = (half_t*)d_ws;
    half_t* Kh = Qh + per;
    half_t* Vt = Kh + per;
    half_t* Wt = Vt + per;                            // 147,456 halfs
    half_t* Opart = Wt + 3 * HS * D_MODEL;
    float*  lpart = (float*)(Opart + (size_t)KSPLIT * per);   // ~23 MB total

    wconv_kernel<<<dim3(3 * HS), dim3(256), 0, stream>>>(Wq, Wk, Wv, Wt);
    proj_kernel<<<dim3(BATCH * SEQ / 32), dim3(256), 0, stream>>>(
        x, Wt, bq, bk, bv, Qh, Kh, Vt);
    attn_kernel<<<dim3(SEQ / 256, BATCH, KSPLIT), dim3(256), 0, stream>>>(
        Qh, Kh, Vt, Opart, lpart);
    combine_kernel<<<dim3((BATCH * SEQ * HS) / (256 * 8)), dim3(256), 0, stream>>>(
        Opart, lpart, out);
}

// Round 12
// 141.178 us; speedup vs baseline: 2.6932x; 1.0042x over previous
//
#include <hip/hip_runtime.h>
#include <math.h>

#define D_MODEL 768
#define HS 64
#define BATCH 8
#define SEQ 2048
#define SCALE 0.125f
#define KSPLIT 8
#define KCHUNK (SEQ / KSPLIT)   // 256

typedef _Float16 half_t;
typedef __attribute__((ext_vector_type(8))) _Float16 half8;
typedef __attribute__((ext_vector_type(4))) float floatx4;

// async global->LDS, 16B per lane, lane-linear LDS destination
typedef const __attribute__((address_space(1))) void gas_void;
typedef __attribute__((address_space(3))) void las_void;
__device__ __forceinline__ void gl_lds16(const void* g, void* l) {
    __builtin_amdgcn_global_load_lds((gas_void*)g, (las_void*)l, 16, 0, 0);
}
__device__ __forceinline__ void waitcnt_all() {
    __builtin_amdgcn_s_waitcnt(0);
}

// ---------------------------------------------------------------
// Kernel 1: W fp32 [D][H] x3 -> Wt fp16 [3*H][D]
// ---------------------------------------------------------------
__global__ __launch_bounds__(256)
void wconv_kernel(const float* __restrict__ Wq, const float* __restrict__ Wk,
                  const float* __restrict__ Wv, half_t* __restrict__ Wt)
{
    int m = blockIdx.x >> 6;
    int h = blockIdx.x & 63;
    const float* W = (m == 0) ? Wq : ((m == 1) ? Wk : Wv);
    half_t* dst = Wt + (size_t)blockIdx.x * D_MODEL;
    for (int k = threadIdx.x; k < D_MODEL; k += 256)
        dst[k] = (half_t)W[(size_t)k * HS + h];
}

// ---------------------------------------------------------------
// Kernel 2: QKV projection. M=64 x N=192 tile (grid 256), parity
// double-buffered LDS, ONE barrier/iter, register prefetch after
// the barrier (R8-proven order). 24 MFMA per wave-iter (2x R11).
// ---------------------------------------------------------------
__global__ __launch_bounds__(256)
void proj_kernel(const float* __restrict__ x, const half_t* __restrict__ Wt,
                 const float* __restrict__ bq, const float* __restrict__ bk,
                 const float* __restrict__ bv,
                 half_t* __restrict__ Qh, half_t* __restrict__ Kh,
                 half_t* __restrict__ Vt)
{
    __shared__ __align__(16) half_t xs[2][64 * 64];    // 2 x 8 KB
    __shared__ __align__(16) half_t wt[2][192 * 64];   // 2 x 24 KB

    const int tid = threadIdx.x;
    const int w = tid >> 6;
    const int lane = tid & 63;
    const int l15 = lane & 15;
    const int quad = lane >> 4;
    const long row0 = (long)blockIdx.x * 64;

    floatx4 acc[4][3];
#pragma unroll
    for (int i = 0; i < 4; ++i)
#pragma unroll
        for (int j = 0; j < 3; ++j) acc[i][j] = (floatx4){0.f, 0.f, 0.f, 0.f};

    float4 xA[4], xB[4];
    half8  wA[6], wB[6];

    auto loadx = [&](int k0, float4 (&v)[4]) {
#pragma unroll
        for (int i = 0; i < 2; ++i) {
            int idx = i * 256 + tid;
            int r = idx >> 3, sc = idx & 7;
            int cg = sc ^ (r & 7);
            const float* p = x + (row0 + r) * D_MODEL + k0 + cg * 8;
            v[i * 2]     = *(const float4*)p;
            v[i * 2 + 1] = *(const float4*)(p + 4);
        }
    };
    auto loadw = [&](int k0, half8 (&wr)[6]) {
#pragma unroll
        for (int i = 0; i < 6; ++i) {
            int idx = i * 256 + tid;
            int r = idx >> 3, sc = idx & 7;
            int cg = sc ^ (r & 7);
            wr[i] = *(const half8*)(Wt + (size_t)r * D_MODEL + k0 + cg * 8);
        }
    };

    auto step = [&](int it, float4 (&xc)[4], half8 (&wc)[6],
                    float4 (&xn)[4], half8 (&wn)[6], int p) {
        // stage current tile into buf p (cvt x -> fp16 in regs)
#pragma unroll
        for (int i = 0; i < 2; ++i) {
            float4 a = xc[i * 2], b = xc[i * 2 + 1];
            half8 xh = (half8){(half_t)a.x, (half_t)a.y, (half_t)a.z, (half_t)a.w,
                               (half_t)b.x, (half_t)b.y, (half_t)b.z, (half_t)b.w};
            *(half8*)&xs[p][(i * 256 + tid) * 8] = xh;
        }
#pragma unroll
        for (int i = 0; i < 6; ++i)
            *(half8*)&wt[p][(i * 256 + tid) * 8] = wc[i];
        __syncthreads();                 // buf p staged across all waves
        // prefetch next tile AFTER barrier -> covered by the MFMA phase
        int kn = (it + 1 < 12) ? (it + 1) * 64 : 0;
        loadx(kn, xn);
        loadw(kn, wn);
        // compute from buf p
#pragma unroll
        for (int kst = 0; kst < 2; ++kst) {
            half8 af[4];
#pragma unroll
            for (int mt = 0; mt < 4; ++mt) {
                int r = mt * 16 + l15;
                int slot = (kst * 4 + quad) ^ (r & 7);
                af[mt] = *(const half8*)&xs[p][r * 64 + slot * 8];
            }
#pragma unroll
            for (int nt = 0; nt < 3; ++nt) {
                int r = w * 48 + nt * 16 + l15;
                int slot = (kst * 4 + quad) ^ (r & 7);
                half8 bf = *(const half8*)&wt[p][r * 64 + slot * 8];
#pragma unroll
                for (int mt = 0; mt < 4; ++mt)
                    acc[mt][nt] = __builtin_amdgcn_mfma_f32_16x16x32_f16(
                        af[mt], bf, acc[mt][nt], 0, 0, 0);
            }
        }
    };

    loadx(0, xA);
    loadw(0, wA);
#pragma unroll
    for (int it = 0; it < 12; it += 2) {
        step(it,     xA, wA, xB, wB, 0);
        step(it + 1, xB, wB, xA, wA, 1);
    }

    // epilogue: bias + fp16 store (n-tiles never straddle 64-boundaries)
#pragma unroll
    for (int nt = 0; nt < 3; ++nt) {
        int nbase = w * 48 + nt * 16;
        int mm = nbase >> 6;
        int h = (nbase + l15) & 63;
        const float* bias = (mm == 0) ? bq : ((mm == 1) ? bk : bv);
        float bval = bias[h];
#pragma unroll
        for (int mt = 0; mt < 4; ++mt)
#pragma unroll
            for (int r = 0; r < 4; ++r) {
                long R = row0 + mt * 16 + quad * 4 + r;
                half_t hv = (half_t)(acc[mt][nt][r] + bval);
                if (mm == 0)      Qh[R * HS + h] = hv;
                else if (mm == 1) Kh[R * HS + h] = hv;
                else {
                    long bb = R >> 11, s = R & 2047;
                    Vt[(bb * HS + h) * SEQ + s] = hv;
                }
            }
    }
}

// ---------------------------------------------------------------
// Kernel 3: flash attention. 2-wave blocks (128 thr, 64 q/wave),
// grid (16,8,8)=1024 -> 4 blocks/CU, 16 waves/CU. gl_lds staging
// + explicit waitcnt (R11-proven). V-frags hoisted per tile.
// ---------------------------------------------------------------
__global__ __launch_bounds__(128)
void attn_kernel(const half_t* __restrict__ Qh, const half_t* __restrict__ Kh,
                 const half_t* __restrict__ Vt,
                 half_t* __restrict__ Opart, float* __restrict__ lpart)
{
    __shared__ __align__(16) half_t ks[64 * 64];      // 8 KB [kk][h] swizzled
    __shared__ __align__(16) half_t vs[64 * 64];      // 8 KB [h][kk] swizzled
    __shared__ __align__(16) half_t ps[2][16][72];    // 4.5 KB per-wave P

    const int tid = threadIdx.x;
    const int w = tid >> 6;
    const int lane = tid & 63;
    const int l15 = lane & 15;
    const int quad = lane >> 4;
    const int b = blockIdx.y;
    const int q0 = blockIdx.x * 128 + w * 64;
    const int kh = blockIdx.z;
    const int kk_begin = kh * KCHUNK;

    const half_t* Kb = Kh + (size_t)b * SEQ * HS;
    const half_t* Vb = Vt + (size_t)b * HS * SEQ;

    half8 qf[4][2];
#pragma unroll
    for (int mt = 0; mt < 4; ++mt)
#pragma unroll
        for (int kst = 0; kst < 2; ++kst) {
            half8 q = *(const half8*)(Qh + ((size_t)b * SEQ + q0 + mt * 16 + l15) * HS
                                      + kst * 32 + quad * 8);
#pragma unroll
            for (int j = 0; j < 8; ++j) q[j] = q[j] * (half_t)SCALE;
            qf[mt][kst] = q;
        }

    floatx4 oacc[4][4];
    float lsum[4][4];
#pragma unroll
    for (int mt = 0; mt < 4; ++mt) {
#pragma unroll
        for (int nt = 0; nt < 4; ++nt) oacc[mt][nt] = (floatx4){0.f, 0.f, 0.f, 0.f};
#pragma unroll
        for (int r = 0; r < 4; ++r) lsum[mt][r] = 0.f;
    }

    for (int it = 0; it < KCHUNK / 64; ++it) {
        const int kk0 = kk_begin + it * 64;
        __syncthreads();   // WAR: previous tile's readers done
        // stage K + V^T: 512+512 half8-chunks (4+4 gl_lds/thread)
#pragma unroll
        for (int i = 0; i < 4; ++i) {
            int idx = i * 128 + tid;
            int r = idx >> 3, sc = idx & 7;
            int cg = sc ^ (r & 7);
            gl_lds16(Kb + (size_t)(kk0 + r) * HS + cg * 8, ks + idx * 8);
            gl_lds16(Vb + (size_t)r * SEQ + kk0 + cg * 8, vs + idx * 8);
        }
        waitcnt_all();     // async LDS writes landed (vmcnt-tracked)
        __syncthreads();   // tiles visible

        // V-fragments into registers once per tile
        half8 vf[4][2];
#pragma unroll
        for (int nt = 0; nt < 4; ++nt)
#pragma unroll
            for (int kst = 0; kst < 2; ++kst) {
                int r = nt * 16 + l15;
                int slot = (kst * 4 + quad) ^ (r & 7);
                vf[nt][kst] = *(const half8*)&vs[r * 64 + slot * 8];
            }

#pragma unroll
        for (int h2 = 0; h2 < 2; ++h2) {
            floatx4 sacc[2][4];
#pragma unroll
            for (int mtl = 0; mtl < 2; ++mtl)
#pragma unroll
                for (int nt = 0; nt < 4; ++nt) sacc[mtl][nt] = (floatx4){0.f, 0.f, 0.f, 0.f};
#pragma unroll
            for (int nt = 0; nt < 4; ++nt)
#pragma unroll
                for (int kst = 0; kst < 2; ++kst) {
                    int r = nt * 16 + l15;
                    int slot = (kst * 4 + quad) ^ (r & 7);
                    half8 kf = *(const half8*)&ks[r * 64 + slot * 8];
#pragma unroll
                    for (int mtl = 0; mtl < 2; ++mtl)
                        sacc[mtl][nt] = __builtin_amdgcn_mfma_f32_16x16x32_f16(
                            qf[h2 * 2 + mtl][kst], kf, sacc[mtl][nt], 0, 0, 0);
                }

#pragma unroll
            for (int mtl = 0; mtl < 2; ++mtl) {
                int mt = h2 * 2 + mtl;
#pragma unroll
                for (int nt = 0; nt < 4; ++nt)
#pragma unroll
                    for (int r = 0; r < 4; ++r) {
                        float pv = __expf(sacc[mtl][nt][r]);
                        lsum[mt][r] += pv;
                        ps[w][quad * 4 + r][nt * 16 + l15] = (half_t)pv;
                    }
                half8 pfr[2];
#pragma unroll
                for (int kst = 0; kst < 2; ++kst)
                    pfr[kst] = *(const half8*)&ps[w][l15][kst * 32 + quad * 8];
#pragma unroll
                for (int nt = 0; nt < 4; ++nt)
#pragma unroll
                    for (int kst = 0; kst < 2; ++kst)
                        oacc[mt][nt] = __builtin_amdgcn_mfma_f32_16x16x32_f16(
                            pfr[kst], vf[nt][kst], oacc[mt][nt], 0, 0, 0);
            }
        }
    }

    // reduce l across the 16 column-lanes of each quad
#pragma unroll
    for (int mt = 0; mt < 4; ++mt)
#pragma unroll
        for (int r = 0; r < 4; ++r) {
            float s = lsum[mt][r];
            s += __shfl_xor(s, 1);
            s += __shfl_xor(s, 2);
            s += __shfl_xor(s, 4);
            s += __shfl_xor(s, 8);
            lsum[mt][r] = s;
        }

    size_t obase = ((size_t)kh * BATCH + b) * SEQ * HS;
#pragma unroll
    for (int mt = 0; mt < 4; ++mt)
#pragma unroll
        for (int nt = 0; nt < 4; ++nt)
#pragma unroll
            for (int r = 0; r < 4; ++r) {
                int row = q0 + mt * 16 + quad * 4 + r;
                Opart[obase + (size_t)row * HS + nt * 16 + l15] = (half_t)oacc[mt][nt][r];
            }
    if (l15 == 0) {
#pragma unroll
        for (int mt = 0; mt < 4; ++mt)
#pragma unroll
            for (int r = 0; r < 4; ++r) {
                int row = q0 + mt * 16 + quad * 4 + r;
                lpart[((size_t)kh * BATCH + b) * SEQ + row] = lsum[mt][r];
            }
    }
}

// ---------------------------------------------------------------
// Kernel 4: combine KSPLIT partials: out = sum(O_i) / sum(l_i)
// ---------------------------------------------------------------
__global__ __launch_bounds__(256)
void combine_kernel(const half_t* __restrict__ Opart, const float* __restrict__ lpart,
                    float* __restrict__ out)
{
    const size_t NT = (size_t)BATCH * SEQ * HS;
    const size_t BS = (size_t)BATCH * SEQ;
    size_t e0 = ((size_t)blockIdx.x * 256 + threadIdx.x) * 8;
    size_t row = e0 / HS;
    float o[8] = {0, 0, 0, 0, 0, 0, 0, 0};
    float l = 0.f;
#pragma unroll
    for (int i = 0; i < KSPLIT; ++i) {
        half8 oi = *(const half8*)(Opart + (size_t)i * NT + e0);
#pragma unroll
        for (int j = 0; j < 8; ++j) o[j] += (float)oi[j];
        l += lpart[(size_t)i * BS + row];
    }
    float inv = 1.f / l;
    float4 a = {o[0] * inv, o[1] * inv, o[2] * inv, o[3] * inv};
    float4 c = {o[4] * inv, o[5] * inv, o[6] * inv, o[7] * inv};
    *(float4*)(out + e0) = a;
    *(float4*)(out + e0 + 4) = c;
}

extern "C" void kernel_launch(void* const* d_in, const int* in_sizes, int n_in,
                              void* d_out, int out_size, void* d_ws, size_t ws_size,
                              hipStream_t stream) {
    const float* x  = (const float*)d_in[0];
    const float* Wq = (const float*)d_in[1];
    const float* bq = (const float*)d_in[2];
    const float* Wk = (const float*)d_in[3];
    const float* bk = (const float*)d_in[4];
    const float* Wv = (const float*)d_in[5];
    const float* bv = (const float*)d_in[6];
    float* out = (float*)d_out;

    const size_t per = (size_t)BATCH * SEQ * HS;      // 1,048,576 elements
    half_t* Qh = (half_t*)d_ws;
    half_t* Kh = Qh + per;
    half_t* Vt = Kh + per;
    half_t* Wt = Vt + per;                            // 147,456 halfs
    half_t* Opart = Wt + 3 * HS * D_MODEL;
    float*  lpart = (float*)(Opart + (size_t)KSPLIT * per);   // ~23 MB total

    wconv_kernel<<<dim3(3 * HS), dim3(256), 0, stream>>>(Wq, Wk, Wv, Wt);
    proj_kernel<<<dim3(BATCH * SEQ / 64), dim3(256), 0, stream>>>(
        x, Wt, bq, bk, bv, Qh, Kh, Vt);
    attn_kernel<<<dim3(SEQ / 128, BATCH, KSPLIT), dim3(128), 0, stream>>>(
        Qh, Kh, Vt, Opart, lpart);
    combine_kernel<<<dim3((BATCH * SEQ * HS) / (256 * 8)), dim3(256), 0, stream>>>(
        Opart, lpart, out);
}